// Round 4
// baseline (1593.144 us; speedup 1.0000x reference)
//
#include <hip/hip_runtime.h>

// PersistentMemory: x[16384,1024], bank[8192,1024]; all fp32 in/out.
// Round 4:
//  - gemm_pl: software-pipelined bf16 NT-GEMM (4-stage LDS ring, raw s_barrier +
//    s_waitcnt vmcnt(8) — never vmcnt(0)) for S-exp and PV (the two big dispatches,
//    both 1 block/CU where the __syncthreads vmcnt(0) drain was the round-3 stall).
//  - gemm_fb: fp32-A GEMM staging fp32 via global_load_lds, cvt at frag-read time
//    (kills the VALU staging tax) for Q and concat GEMMs.
//  - bank + weights pre-converted to bf16 (ws total 91 MB < proven 96 MB).

typedef __bf16 bf16;
typedef __bf16 bf16x4 __attribute__((ext_vector_type(4)));
typedef __bf16 bf16x8 __attribute__((ext_vector_type(8)));
typedef float f32x4 __attribute__((ext_vector_type(4)));

static __device__ __forceinline__ f32x4 mfma16(bf16x8 a, bf16x8 b, f32x4 c) {
  return __builtin_amdgcn_mfma_f32_16x16x32_bf16(a, b, c, 0, 0, 0);
}

// async global->LDS, 16B per lane; LDS dest = wave-uniform base + lane*16
#define GLDS16(gp, lp) __builtin_amdgcn_global_load_lds( \
    (const __attribute__((address_space(1))) void*)(gp), \
    (__attribute__((address_space(3))) void*)(lp), 16, 0, 0)

// s_waitcnt immediates (gfx9 encoding: vmcnt lo [3:0] hi [15:14], exp [6:4], lgkm [11:8])
#define WAIT_VM8   0xF78   // vmcnt(8),  lgkm/exp no-wait
#define WAIT_VM4   0xF74   // vmcnt(4)
#define WAIT_VM0   0xF70   // vmcnt(0)
#define WAIT_LGKM0 0xC07F  // lgkmcnt(0), vmcnt/exp no-wait

// ---------------------------------------------------------------------------
// gemm_pl: pipelined bf16 NT-GEMM  C[M,N] = A[M,K] @ W[N,K]^T.
// 512 thr = 8 waves (4 row-groups x 2 col-groups, wave tile 32x64), 128x128
// tile, BK=64, 4-stage LDS ring (128 KB). One raw s_barrier per K-iter with
// s_waitcnt vmcnt(8): stage k's 4 loads drained, stages k+1/k+2 stay in flight.
// Single-barrier safety: stage k+3 writes buf (k+3)&3 == (k-1)&3, whose last
// readers (compute k-1) precede barrier_k in every wave's program order.
// lgkmcnt(0) before the barrier = the ds_read drain __syncthreads used to do.
// EPI 0: C = bf16(exp(acc/32)) stride N, rowsum atomicAdd -> L   (S-exp)
// EPI 1: C = bf16(acc / L[row]) stride N                          (PV)
// ---------------------------------------------------------------------------
template<int EPI>
__global__ __launch_bounds__(512, 1) void gemm_pl(
    const bf16* __restrict__ A, const bf16* __restrict__ W,
    float* __restrict__ L, bf16* __restrict__ C, int N, int K)
{
  __shared__ bf16 SA[4][128 * 64];   // 64 KB
  __shared__ bf16 SB[4][128 * 64];   // 64 KB
  const int tid = threadIdx.x, lane = tid & 63, wid = tid >> 6;
  const int wm = (wid & 3) * 32, wn = (wid >> 2) * 64;
  const int quad = lane >> 4, l16 = lane & 15;
  const long bm = (long)blockIdx.y * 128, bn = (long)blockIdx.x * 128;

  // staging: 2 GLDS16 per thread per array; 16B slot p = (wid*2+i)*64 + lane;
  // slot p holds logical (row = p>>3, colgroup = (p&7) ^ (row&7))  [XOR swizzle]
  int arow[2], acg[2];
#pragma unroll
  for (int i = 0; i < 2; ++i) {
    int p = ((wid * 2 + i) << 6) + lane;
    arow[i] = p >> 3;
    acg[i] = (p & 7) ^ (arow[i] & 7);
  }
  const int NIT = K >> 6;

  f32x4 acc[2][4] = {};

  auto stage = [&](int s, int buf) {
    const int k0 = s << 6;
#pragma unroll
    for (int i = 0; i < 2; ++i)
      GLDS16(A + (size_t)(bm + arow[i]) * K + k0 + acg[i] * 8,
             (char*)SA[buf] + ((wid * 2 + i) << 10));
#pragma unroll
    for (int i = 0; i < 2; ++i)
      GLDS16(W + (size_t)(bn + arow[i]) * K + k0 + acg[i] * 8,
             (char*)SB[buf] + ((wid * 2 + i) << 10));
  };
  auto compute = [&](int buf) {
#pragma unroll
    for (int kk = 0; kk < 2; ++kk) {
      bf16x8 af[2], bv[4];
#pragma unroll
      for (int mt = 0; mt < 2; ++mt) {
        const int r = wm + mt * 16 + l16;
        af[mt] = *(const bf16x8*)((const char*)SA[buf] + (r << 7)
                                  + ((((kk << 2) + quad) ^ (r & 7)) << 4));
      }
#pragma unroll
      for (int nt = 0; nt < 4; ++nt) {
        const int r = wn + nt * 16 + l16;
        bv[nt] = *(const bf16x8*)((const char*)SB[buf] + (r << 7)
                                  + ((((kk << 2) + quad) ^ (r & 7)) << 4));
      }
#pragma unroll
      for (int mt = 0; mt < 2; ++mt)
#pragma unroll
        for (int nt = 0; nt < 4; ++nt)
          acc[mt][nt] = mfma16(af[mt], bv[nt], acc[mt][nt]);
    }
  };

  stage(0, 0); stage(1, 1); stage(2, 2);   // 12 loads in flight per wave
  for (int k = 0; k < NIT; ++k) {
    if (k < NIT - 2)       __builtin_amdgcn_s_waitcnt(WAIT_VM8);
    else if (k == NIT - 2) __builtin_amdgcn_s_waitcnt(WAIT_VM4);
    else                   __builtin_amdgcn_s_waitcnt(WAIT_VM0);
    __builtin_amdgcn_s_waitcnt(WAIT_LGKM0);
    __builtin_amdgcn_s_barrier();
    if (k + 3 < NIT) stage(k + 3, (k + 3) & 3);
    compute(k & 3);
  }

#pragma unroll
  for (int mt = 0; mt < 2; ++mt) {
    const long row0 = bm + wm + mt * 16 + quad * 4;
    if (EPI == 0) {
      float rsum[4] = {0.f, 0.f, 0.f, 0.f};
#pragma unroll
      for (int nt = 0; nt < 4; ++nt) {
        const long col = bn + wn + nt * 16 + l16;
#pragma unroll
        for (int r = 0; r < 4; ++r) {
          float p = __expf(acc[mt][nt][r] * 0.03125f);
          rsum[r] += p;
          C[(size_t)(row0 + r) * N + col] = (bf16)p;
        }
      }
#pragma unroll
      for (int s = 1; s < 16; s <<= 1)
#pragma unroll
        for (int r = 0; r < 4; ++r) rsum[r] += __shfl_xor(rsum[r], s, 64);
      if (l16 == 0) {
#pragma unroll
        for (int r = 0; r < 4; ++r) atomicAdd(&L[row0 + r], rsum[r]);
      }
    } else {
      float linv[4];
#pragma unroll
      for (int r = 0; r < 4; ++r) linv[r] = 1.f / L[row0 + r];
#pragma unroll
      for (int nt = 0; nt < 4; ++nt) {
        const long col = bn + wn + nt * 16 + l16;
#pragma unroll
        for (int r = 0; r < 4; ++r)
          C[(size_t)(row0 + r) * N + col] = (bf16)(acc[mt][nt][r] * linv[r]);
      }
    }
  }
}

// ---------------------------------------------------------------------------
// gemm_bb: non-pipelined all-bf16 NT-GEMM (m97 structure) for K / Vt GEMMs.
// 256 thr, 128x128, BK=64. EPI 0: bias[col]; EPI 1: bias[row]. bf16 out.
// ---------------------------------------------------------------------------
template<int EPI>
__global__ __launch_bounds__(256, 3) void gemm_bb(
    const bf16* __restrict__ A, const bf16* __restrict__ W,
    const float* __restrict__ bias, bf16* __restrict__ C, int N, int K)
{
  __shared__ bf16 As[128 * 64];
  __shared__ bf16 Bs[128 * 64];
  const int tid = threadIdx.x, lane = tid & 63, wid = tid >> 6;
  const int wm = (wid >> 1) * 64, wn = (wid & 1) * 64;
  const int quad = lane >> 4, l16 = lane & 15;
  const long bm = (long)blockIdx.y * 128, bn = (long)blockIdx.x * 128;

  int prow[4], pcg[4];
#pragma unroll
  for (int i = 0; i < 4; ++i) {
    int p = ((wid * 4 + i) << 6) + lane;
    prow[i] = p >> 3;
    pcg[i] = (p & 7) ^ (prow[i] & 7);
  }

  f32x4 acc[4][4] = {};

  for (int k0 = 0; k0 < K; k0 += 64) {
    __syncthreads();
#pragma unroll
    for (int i = 0; i < 4; ++i)
      GLDS16(A + (size_t)(bm + prow[i]) * K + k0 + pcg[i] * 8,
             (char*)As + ((wid * 4 + i) << 10));
#pragma unroll
    for (int i = 0; i < 4; ++i)
      GLDS16(W + (size_t)(bn + prow[i]) * K + k0 + pcg[i] * 8,
             (char*)Bs + ((wid * 4 + i) << 10));
    __syncthreads();
#pragma unroll
    for (int kk = 0; kk < 2; ++kk) {
      bf16x8 af[4], bfv[4];
#pragma unroll
      for (int mt = 0; mt < 4; ++mt) {
        const int r = wm + mt * 16 + l16;
        af[mt] = *(const bf16x8*)((const char*)As + (r << 7)
                                  + ((((kk << 2) + quad) ^ (r & 7)) << 4));
      }
#pragma unroll
      for (int nt = 0; nt < 4; ++nt) {
        const int r = wn + nt * 16 + l16;
        bfv[nt] = *(const bf16x8*)((const char*)Bs + (r << 7)
                                   + ((((kk << 2) + quad) ^ (r & 7)) << 4));
      }
#pragma unroll
      for (int mt = 0; mt < 4; ++mt)
#pragma unroll
        for (int nt = 0; nt < 4; ++nt)
          acc[mt][nt] = mfma16(af[mt], bfv[nt], acc[mt][nt]);
    }
  }

#pragma unroll
  for (int mt = 0; mt < 4; ++mt) {
    const long row0 = bm + wm + mt * 16 + quad * 4;
#pragma unroll
    for (int nt = 0; nt < 4; ++nt) {
      const long col = bn + wn + nt * 16 + l16;
      const float bc = (EPI == 1) ? 0.f : bias[col];
#pragma unroll
      for (int r = 0; r < 4; ++r) {
        float v = acc[mt][nt][r] + ((EPI == 1) ? bias[row0 + r] : bc);
        C[(size_t)(row0 + r) * N + col] = (bf16)v;
      }
    }
  }
}

// ---------------------------------------------------------------------------
// gemm_fb: C[M,N] = A[M,K] @ W[N,K]^T with fp32 A staged RAW via global_load_lds
// (32 KB fp32 LDS tile) and converted to bf16 at frag-read time; W is bf16.
// 256 thr, 128x128, BK=64, 48 KB LDS. A stride fixed 1024 (= x).
// EPI 0: C bf16 = acc + bias[col]                         (Q GEMM, K=1024)
// EPI 1: C f32  = acc + bias[col] + resid[row*1024+col]   (concat GEMM, K=2048;
//        k0 >= 1024 reads A2 = retrieved, bf16, stride 1024)
// ---------------------------------------------------------------------------
template<int EPI>
__global__ __launch_bounds__(256, 3) void gemm_fb(
    const float* __restrict__ A, const bf16* __restrict__ A2,
    const bf16* __restrict__ W, const float* __restrict__ bias,
    const float* __restrict__ resid, void* __restrict__ Cout, int N, int K)
{
  __shared__ float Af[128 * 64];   // 32 KB (also reused as bf16 region, phase 2)
  __shared__ bf16 Bs[128 * 64];    // 16 KB
  const int tid = threadIdx.x, lane = tid & 63, wid = tid >> 6;
  const int wm = (wid >> 1) * 64, wn = (wid & 1) * 64;
  const int quad = lane >> 4, l16 = lane & 15;
  const long bm = (long)blockIdx.y * 128, bn = (long)blockIdx.x * 128;

  // fp32-A staging: 8 slots/thread; slot p: row = p>>4, grp = (p&15)^(row&15)
  int frow[8], fg[8];
#pragma unroll
  for (int i = 0; i < 8; ++i) {
    int p = ((wid * 8 + i) << 6) + lane;
    frow[i] = p >> 4;
    fg[i] = (p & 15) ^ (frow[i] & 15);
  }
  // bf16 staging (B always; A2 in phase 2): row = p>>3, cg = (p&7)^(row&7)
  int prow[4], pcg[4];
#pragma unroll
  for (int i = 0; i < 4; ++i) {
    int p = ((wid * 4 + i) << 6) + lane;
    prow[i] = p >> 3;
    pcg[i] = (p & 7) ^ (prow[i] & 7);
  }

  f32x4 acc[4][4] = {};

  for (int k0 = 0; k0 < K; k0 += 64) {
    const bool ph2 = (EPI == 1) && (k0 >= 1024);
    __syncthreads();
    if (!ph2) {
#pragma unroll
      for (int i = 0; i < 8; ++i)
        GLDS16(A + (size_t)(bm + frow[i]) * 1024 + k0 + fg[i] * 4,
               (char*)Af + ((wid * 8 + i) << 10));
    } else {
#pragma unroll
      for (int i = 0; i < 4; ++i)
        GLDS16(A2 + (size_t)(bm + prow[i]) * 1024 + (k0 - 1024) + pcg[i] * 8,
               (char*)Af + ((wid * 4 + i) << 10));
    }
#pragma unroll
    for (int i = 0; i < 4; ++i)
      GLDS16(W + (size_t)(bn + prow[i]) * K + k0 + pcg[i] * 8,
             (char*)Bs + ((wid * 4 + i) << 10));
    __syncthreads();
#pragma unroll
    for (int kk = 0; kk < 2; ++kk) {
      bf16x8 af[4], bfv[4];
#pragma unroll
      for (int mt = 0; mt < 4; ++mt) {
        const int r = wm + mt * 16 + l16;
        if (!ph2) {
          const int g0 = kk * 8 + quad * 2;
          f32x4 lo = *(const f32x4*)((const char*)Af + (r << 8)
                                     + ((g0 ^ (r & 15)) << 4));
          f32x4 hi = *(const f32x4*)((const char*)Af + (r << 8)
                                     + (((g0 + 1) ^ (r & 15)) << 4));
#pragma unroll
          for (int j = 0; j < 4; ++j) { af[mt][j] = (bf16)lo[j]; af[mt][4 + j] = (bf16)hi[j]; }
        } else {
          af[mt] = *(const bf16x8*)((const char*)Af + (r << 7)
                                    + ((((kk << 2) + quad) ^ (r & 7)) << 4));
        }
      }
#pragma unroll
      for (int nt = 0; nt < 4; ++nt) {
        const int r = wn + nt * 16 + l16;
        bfv[nt] = *(const bf16x8*)((const char*)Bs + (r << 7)
                                   + ((((kk << 2) + quad) ^ (r & 7)) << 4));
      }
#pragma unroll
      for (int mt = 0; mt < 4; ++mt)
#pragma unroll
        for (int nt = 0; nt < 4; ++nt)
          acc[mt][nt] = mfma16(af[mt], bfv[nt], acc[mt][nt]);
    }
  }

#pragma unroll
  for (int mt = 0; mt < 4; ++mt) {
    const long row0 = bm + wm + mt * 16 + quad * 4;
#pragma unroll
    for (int nt = 0; nt < 4; ++nt) {
      const long col = bn + wn + nt * 16 + l16;
      const float bc = bias[col];
#pragma unroll
      for (int r = 0; r < 4; ++r) {
        float v = acc[mt][nt][r] + bc;
        if (EPI == 1) {
          v += resid[(size_t)(row0 + r) * 1024 + col];
          ((float*)Cout)[(size_t)(row0 + r) * N + col] = v;
        } else {
          ((bf16*)Cout)[(size_t)(row0 + r) * N + col] = (bf16)v;
        }
      }
    }
  }
}

// ---------------------------------------------------------------------------
// fp32 -> bf16 bulk convert: bank + wq + wk + wv + wf (f32x4 per thread).
// ---------------------------------------------------------------------------
__global__ __launch_bounds__(256) void cvt5(
    const float* __restrict__ bank, const float* __restrict__ wq,
    const float* __restrict__ wk, const float* __restrict__ wv,
    const float* __restrict__ wf, bf16* __restrict__ bankb,
    bf16* __restrict__ wqb, bf16* __restrict__ wkb,
    bf16* __restrict__ wvb, bf16* __restrict__ wfb)
{
  long i4 = (long)blockIdx.x * 256 + threadIdx.x;
  const float* src; bf16* dst; long off;
  if      (i4 < 2097152) { src = bank; dst = bankb; off = i4; }
  else if (i4 < 2359296) { src = wq;   dst = wqb;   off = i4 - 2097152; }
  else if (i4 < 2621440) { src = wk;   dst = wkb;   off = i4 - 2359296; }
  else if (i4 < 2883584) { src = wv;   dst = wvb;   off = i4 - 2621440; }
  else                   { src = wf;   dst = wfb;   off = i4 - 2883584; }
  f32x4 v = ((const f32x4*)src)[off];
  bf16x4 o;
#pragma unroll
  for (int j = 0; j < 4; ++j) o[j] = (bf16)v[j];
  ((bf16x4*)dst)[off] = o;
}

__global__ __launch_bounds__(256) void zerof(float* __restrict__ p) {
  p[(size_t)blockIdx.x * 256 + threadIdx.x] = 0.f;
}

// ---------------------------------------------------------------------------
// In-place LayerNorm over last dim (1024). One block per row, 256 threads x4.
// ---------------------------------------------------------------------------
__global__ __launch_bounds__(256) void ln_kernel(
    float* __restrict__ h, const float* __restrict__ g, const float* __restrict__ b)
{
  const int tid = threadIdx.x;
  const size_t row = blockIdx.x;
  f32x4 v = *(f32x4*)&h[row * 1024 + tid * 4];
  float s1 = v[0] + v[1] + v[2] + v[3];
  float s2 = v[0]*v[0] + v[1]*v[1] + v[2]*v[2] + v[3]*v[3];
#pragma unroll
  for (int d = 1; d < 64; d <<= 1) { s1 += __shfl_xor(s1, d, 64); s2 += __shfl_xor(s2, d, 64); }
  __shared__ float a1[4], a2[4];
  const int wid = tid >> 6;
  if ((tid & 63) == 0) { a1[wid] = s1; a2[wid] = s2; }
  __syncthreads();
  s1 = a1[0] + a1[1] + a1[2] + a1[3];
  s2 = a2[0] + a2[1] + a2[2] + a2[3];
  const float mu = s1 * (1.f / 1024.f);
  const float rs = rsqrtf(s2 * (1.f / 1024.f) - mu * mu + 1e-5f);
  f32x4 gv = *(const f32x4*)&g[tid * 4];
  f32x4 bv = *(const f32x4*)&b[tid * 4];
#pragma unroll
  for (int j = 0; j < 4; ++j) v[j] = (v[j] - mu) * rs * gv[j] + bv[j];
  *(f32x4*)&h[row * 1024 + tid * 4] = v;
}

// ---------------------------------------------------------------------------
extern "C" void kernel_launch(void* const* d_in, const int* in_sizes, int n_in,
                              void* d_out, int out_size, void* d_ws, size_t ws_size,
                              hipStream_t stream)
{
  const float* x     = (const float*)d_in[0];
  const float* kbank = (const float*)d_in[1];
  const float* wq    = (const float*)d_in[2];
  const float* bq    = (const float*)d_in[3];
  const float* wk    = (const float*)d_in[4];
  const float* bk    = (const float*)d_in[5];
  const float* wv    = (const float*)d_in[6];
  const float* bv    = (const float*)d_in[7];
  const float* wf    = (const float*)d_in[8];
  const float* bf_   = (const float*)d_in[9];
  const float* gamma = (const float*)d_in[10];
  const float* beta  = (const float*)d_in[11];

  // ws layout (MB offsets), total 91 MB < proven 96 MB:
  //   [0,32)  Qb bf16[16384,1024]   (aliased as Rb after S-exp consumes it)
  //   [32,48) Kb bf16[8192,1024]
  //   [48,64) Vt bf16[1024,8192]
  //   [64,+64K) L f32[16384]
  //   [65,67) wqb  [67,69) wkb  [69,71) wvb  [71,75) wfb  [75,91) bankb
  // P (bf16, 4096x8192 per chunk) lives in d_out (64 MB), dead until concat GEMM.
  char* ws = (char*)d_ws;
  const size_t MB = 1024 * 1024;
  bf16*  Qb    = (bf16*)ws;
  bf16*  Rb    = Qb;
  bf16*  Kb    = (bf16*)(ws + 32 * MB);
  bf16*  Vt    = (bf16*)(ws + 48 * MB);
  float* L     = (float*)(ws + 64 * MB);
  bf16*  wqb   = (bf16*)(ws + 65 * MB);
  bf16*  wkb   = (bf16*)(ws + 67 * MB);
  bf16*  wvb   = (bf16*)(ws + 69 * MB);
  bf16*  wfb   = (bf16*)(ws + 71 * MB);
  bf16*  bankb = (bf16*)(ws + 75 * MB);
  bf16*  P     = (bf16*)d_out;
  float* out   = (float*)d_out;

  // bf16 conversions: bank + all four weights
  cvt5<<<dim3(13312), dim3(256), 0, stream>>>(
      kbank, wq, wk, wv, wf, bankb, wqb, wkb, wvb, wfb);

  // queries = x @ wq^T + bq   (fp32 A via GLDS, frag-time cvt)
  gemm_fb<0><<<dim3(8, 128), dim3(256), 0, stream>>>(
      x, nullptr, wqb, bq, nullptr, (void*)Qb, 1024, 1024);
  // keys = bank @ wk^T + bk
  gemm_bb<0><<<dim3(8, 64), dim3(256), 0, stream>>>(
      bankb, wkb, bk, Kb, 1024, 1024);
  // Vt = (bank @ wv^T)^T: A=wvb (M=1024), W=bankb (N=8192), bias per-row
  gemm_bb<1><<<dim3(64, 8), dim3(256), 0, stream>>>(
      wvb, bankb, bv, Vt, 8192, 1024);

  zerof<<<dim3(64), dim3(256), 0, stream>>>(L);
  for (int c = 0; c < 4; ++c) {
    // P = exp(Q_chunk Kb^T / 32) into d_out; rowsums -> L  (pipelined)
    gemm_pl<0><<<dim3(64, 32), dim3(512), 0, stream>>>(
        Qb + (size_t)c * 4096 * 1024, Kb, L + c * 4096, P, 8192, 1024);
    // Rb_chunk = (P Vt^T) / L   (pipelined; overwrites consumed Qb chunk)
    gemm_pl<1><<<dim3(8, 32), dim3(512), 0, stream>>>(
        P, Vt, L + c * 4096, Rb + (size_t)c * 4096 * 1024, 1024, 8192);
  }

  // h = [x, retrieved] @ wf^T + bf + x -> d_out (fp32); P dead now
  gemm_fb<1><<<dim3(8, 128), dim3(256), 0, stream>>>(
      x, Rb, wfb, bf_, x, (void*)out, 1024, 2048);
  // LayerNorm in place
  ln_kernel<<<dim3(16384), dim3(256), 0, stream>>>(out, gamma, beta);
}